// Round 7
// baseline (293.936 us; speedup 1.0000x reference)
//
#include <hip/hip_runtime.h>

// Sparse submanifold 3x3x3 conv (64->64) + BatchNorm(batch stats) + LeakyReLU(0.01)
// Rulebook strategy, occupancy bitmask, contention-free counters.
//   K1 memset cnt/stats (20KB) + occ bitmask (1.2MB)
//   K2 scatter: grid[lin]=i, atomicOr occ bit
//   K3 rulebook (block-aggregated LDS staging, padded global reservation)
//   K4 center GEMM: out = feat @ W[13]; 8 rows x 8 ch per thread (register-blocked,
//      LDS traffic 2.4GB -> 307MB); plain store => initializes out
//   K5 per-offset gather-GEMM: wave-per-2-pairs, lane=channel, coalesced atomics
//   K6 channel sum/sumsq reduction (padded atomics)
//   K7 normalize + leaky relu (in place on out)

#define DD 96
#define HH 320
#define WW 320
#define GRID_ELEMS (DD * HH * WW)
#define OCC_WORDS (GRID_ELEMS / 32)   // 1.2 MB; WW%32==0 => rows word-aligned
#define CIN 64
#define COUT 64
#define PAIR_CAP 16384
#define STAGE_CAP 40    // per-(block,k) staging; mean 3.9 hits, P(>40) ~ 0
#define EPSV 1e-5f
#define SLOPE 0.01f

__global__ void scatter_k(const int* __restrict__ coords, int* __restrict__ grid,
                          unsigned* __restrict__ occ, int N) {
    int i = blockIdx.x * 256 + threadIdx.x;
    if (i >= N) return;
    int z = coords[3 * i], y = coords[3 * i + 1], x = coords[3 * i + 2];
    int l = (z * HH + y) * WW + x;
    grid[l] = i;
    atomicOr(&occ[l >> 5], 1u << (l & 31));
}

// Per-voxel probe of L2-resident bitmask; hits staged in LDS; one padded global
// atomic per (block,k) reserves the compact range; bulk copy-out.
__global__ void rulebook_k(const int* __restrict__ coords, const int* __restrict__ grid,
                           const unsigned* __restrict__ occ,
                           int* __restrict__ cnt, int2* __restrict__ pairs, int N) {
    __shared__ int scnt[27];
    __shared__ int sbase[27];
    __shared__ int2 stage[27][STAGE_CAP];
    int tid = threadIdx.x;
    if (tid < 27) scnt[tid] = 0;
    __syncthreads();

    int i = blockIdx.x * 256 + tid;
    if (i < N) {
        int z = coords[3 * i], y = coords[3 * i + 1], x = coords[3 * i + 2];
        int lo = x > 0 ? x - 1 : 0;
        int hi = x < WW - 1 ? x + 1 : WW - 1;
        int wlo = lo >> 5, whi = hi >> 5;

        unsigned wa[9], wb9[9];
        int rwb[9];
#pragma unroll
        for (int r = 0; r < 9; ++r) {
            int zz = z + r / 3 - 1;
            int yy = y + r % 3 - 1;
            bool ok = ((unsigned)zz < DD) && ((unsigned)yy < HH);
            int base = (zz * HH + yy) * WW;      // word-aligned (WW % 32 == 0)
            rwb[r] = base;
            int wbase = base >> 5;
            wa[r]  = ok ? occ[wbase + wlo] : 0u;
            wb9[r] = ok ? occ[wbase + whi] : 0u;
        }
#pragma unroll
        for (int r = 0; r < 9; ++r) {
            for (int xx = lo; xx <= hi; ++xx) {
                if (r == 4 && xx == x) continue;          // center handled by center_k
                unsigned w = ((xx >> 5) == wlo) ? wa[r] : wb9[r];
                if ((w >> (xx & 31)) & 1u) {
                    int j = grid[rwb[r] + xx];
                    int k = r * 3 + (xx - x + 1);         // 0..26, never 13
                    int pos = atomicAdd(&scnt[k], 1);     // LDS atomic: cheap
                    if (pos < STAGE_CAP) stage[k][pos] = make_int2(i, j);
                }
            }
        }
    }
    __syncthreads();
    if (tid < 27) {
        int c = scnt[tid];
        if (c > STAGE_CAP) c = STAGE_CAP;
        scnt[tid] = c;
        if (c > 0) sbase[tid] = atomicAdd(&cnt[tid * 32], c);  // 128B-padded counters
    }
    __syncthreads();
    for (int s = tid; s < 27 * STAGE_CAP; s += 256) {
        int k = s / STAGE_CAP, p = s % STAGE_CAP;
        if (p < scnt[k]) {
            int pos = sbase[k] + p;
            if (pos < PAIR_CAP) pairs[k * PAIR_CAP + pos] = stage[k][p];
        }
    }
}

// Register-blocked dense GEMM: thread = 8 rows x 8 channels. LDS reads amortized
// 8x over rows (8 dwords/output vs 64). All inner loops statically unrolled;
// acc[] only ever indexed by compile-time constants.
__global__ void center_k(const float* __restrict__ feat, const float* __restrict__ w13,
                         float* __restrict__ out, int N) {
    __shared__ float wl[CIN * COUT];
    {
        const float4* ws4 = (const float4*)w13;
        float4* wl4 = (float4*)wl;
        for (int t = threadIdx.x; t < CIN * COUT / 4; t += 256) wl4[t] = ws4[t];
    }
    __syncthreads();
    int c0 = (threadIdx.x & 7) * 8;                       // 8-channel group
    int r0 = blockIdx.x * 256 + (threadIdx.x >> 3) * 8;   // 8-row group
    if (r0 >= N) return;
    bool ok[8];
#pragma unroll
    for (int r = 0; r < 8; ++r) ok[r] = (r0 + r) < N;

    float4 acc[8][2];
#pragma unroll
    for (int r = 0; r < 8; ++r) {
        acc[r][0] = make_float4(0.f, 0.f, 0.f, 0.f);
        acc[r][1] = make_float4(0.f, 0.f, 0.f, 0.f);
    }
    const float4* f4 = (const float4*)feat;
#pragma unroll 4
    for (int ci4 = 0; ci4 < 16; ++ci4) {
        float4 f[8];
#pragma unroll
        for (int r = 0; r < 8; ++r) {
            int rr = ok[r] ? (r0 + r) : 0;                // safe clamp; dead rows unstored
            f[r] = f4[(size_t)rr * 16 + ci4];
        }
#pragma unroll
        for (int u = 0; u < 4; ++u) {
            float4 wa = *(const float4*)&wl[(ci4 * 4 + u) * COUT + c0];
            float4 wb = *(const float4*)&wl[(ci4 * 4 + u) * COUT + c0 + 4];
#pragma unroll
            for (int r = 0; r < 8; ++r) {
                float fv = (&f[r].x)[u];
                acc[r][0].x += fv * wa.x;
                acc[r][0].y += fv * wa.y;
                acc[r][0].z += fv * wa.z;
                acc[r][0].w += fv * wa.w;
                acc[r][1].x += fv * wb.x;
                acc[r][1].y += fv * wb.y;
                acc[r][1].z += fv * wb.z;
                acc[r][1].w += fv * wb.w;
            }
        }
    }
    float4* o4 = (float4*)out;
#pragma unroll
    for (int r = 0; r < 8; ++r) {
        if (ok[r]) {
            size_t base = (size_t)(r0 + r) * 16 + (c0 >> 2);
            o4[base] = acc[r][0];
            o4[base + 1] = acc[r][1];
        }
    }
}

// Wave-per-2-pairs: lane = output channel; each wl read feeds both accumulators.
// f[j] float4 reads are wave-uniform (broadcast); atomicAdd per pair is ONE
// contiguous 256B region (4 lines).
__global__ void offset_k(const float* __restrict__ feat, const float* __restrict__ weight,
                         const int2* __restrict__ pairs, const int* __restrict__ cnt,
                         float* __restrict__ out) {
    int k = blockIdx.y;
    if (k >= 13) ++k;  // skip center
    int ck = cnt[k * 32];
    if (ck > PAIR_CAP) ck = PAIR_CAP;
    __shared__ float wl[CIN * COUT];
    {
        const float4* ws4 = (const float4*)(weight + (size_t)k * CIN * COUT);
        float4* wl4 = (float4*)wl;
        for (int t = threadIdx.x; t < CIN * COUT / 4; t += 256) wl4[t] = ws4[t];
    }
    __syncthreads();
    int wave = threadIdx.x >> 6;   // 0..3
    int lane = threadIdx.x & 63;   // output channel
    for (int p = (int)blockIdx.x * 8 + wave * 2; p < ck; p += (int)gridDim.x * 8) {
        int2 prA = pairs[k * PAIR_CAP + p];
        bool hasB = (p + 1) < ck;
        int2 prB = hasB ? pairs[k * PAIR_CAP + p + 1] : prA;
        const float4* frA = (const float4*)(feat + (size_t)prA.y * CIN);
        const float4* frB = (const float4*)(feat + (size_t)prB.y * CIN);
        float accA = 0.f, accB = 0.f;
#pragma unroll
        for (int ci4 = 0; ci4 < CIN / 4; ++ci4) {
            float4 fa = frA[ci4];                       // wave-uniform -> broadcast
            float4 fb = frB[ci4];
#pragma unroll
            for (int u = 0; u < 4; ++u) {
                float w = wl[(ci4 * 4 + u) * COUT + lane];
                accA += (&fa.x)[u] * w;
                accB += (&fb.x)[u] * w;
            }
        }
        atomicAdd(&out[(size_t)prA.x * COUT + lane], accA);  // coalesced 256B region
        if (hasB) atomicAdd(&out[(size_t)prB.x * COUT + lane], accB);
    }
}

// Padded stats: stats[c*32] = sum_c, stats[(64+c)*32] = sumsq_c (128B per counter)
__global__ void stats_k(const float* __restrict__ out, float* __restrict__ stats, int N) {
    __shared__ float ssum[4][64];
    __shared__ float ssq[4][64];
    int c = threadIdx.x & 63, g = threadIdx.x >> 6;
    float s = 0.f, q = 0.f;
    for (int r = blockIdx.x * 4 + g; r < N; r += gridDim.x * 4) {
        float v = out[(size_t)r * 64 + c];
        s += v;
        q += v * v;
    }
    ssum[g][c] = s;
    ssq[g][c] = q;
    __syncthreads();
    if (threadIdx.x < 64) {
        float ts = ssum[0][c] + ssum[1][c] + ssum[2][c] + ssum[3][c];
        float tq = ssq[0][c] + ssq[1][c] + ssq[2][c] + ssq[3][c];
        atomicAdd(&stats[c * 32], ts);
        atomicAdd(&stats[(64 + c) * 32], tq);
    }
}

__global__ void norm_k(float* __restrict__ out, const float* __restrict__ stats,
                       const float* __restrict__ gamma, const float* __restrict__ beta, int N) {
    int idx = (int)blockIdx.x * 256 + threadIdx.x;
    int total = N * (COUT / 4);
    if (idx >= total) return;
    int c0 = (idx & 15) * 4;
    float inv = 1.0f / (float)N;
    float4 v = ((const float4*)out)[idx];
    float4 r;
#pragma unroll
    for (int u = 0; u < 4; ++u) {
        int c = c0 + u;
        float mean = stats[c * 32] * inv;
        float var = stats[(64 + c) * 32] * inv - mean * mean;
        if (var < 0.f) var = 0.f;
        float sc = gamma[c] * rsqrtf(var + EPSV);
        float sh = beta[c] - mean * sc;
        float y = (&v.x)[u] * sc + sh;
        (&r.x)[u] = (y >= 0.f) ? y : SLOPE * y;
    }
    ((float4*)out)[idx] = r;
}

extern "C" void kernel_launch(void* const* d_in, const int* in_sizes, int n_in,
                              void* d_out, int out_size, void* d_ws, size_t ws_size,
                              hipStream_t stream) {
    const float* feat   = (const float*)d_in[0];
    const int*   coords = (const int*)d_in[1];
    const float* weight = (const float*)d_in[2];
    const float* gamma  = (const float*)d_in[3];
    const float* beta   = (const float*)d_in[4];
    float* out = (float*)d_out;
    int N = in_sizes[0] / CIN;

    // workspace layout (~44.1 MB)
    char* ws = (char*)d_ws;
    int* grid = (int*)ws;                                   // 39.32 MB (gated by occ, no memset)
    size_t off = (size_t)GRID_ELEMS * 4;
    int* cnt = (int*)(ws + off);                            // 27*32 ints padded -> 4KB slot
    float* stats = (float*)(ws + off + 4096);               // 128*32 floats padded = 16KB
    int2* pairs = (int2*)(ws + off + 4096 + 16384);         // 27*PAIR_CAP*8 = 3.54 MB
    size_t occ_off = off + 4096 + 16384 + (size_t)27 * PAIR_CAP * 8;
    unsigned* occ = (unsigned*)(ws + occ_off);              // 1.2 MB bitmask

    hipMemsetAsync(ws + off, 0, 4096 + 16384, stream);      // counters + stats
    hipMemsetAsync(occ, 0, (size_t)OCC_WORDS * 4, stream);  // bitmask = 0

    int nb = (N + 255) / 256;
    scatter_k<<<nb, 256, 0, stream>>>(coords, grid, occ, N);
    rulebook_k<<<nb, 256, 0, stream>>>(coords, grid, occ, cnt, pairs, N);
    center_k<<<nb, 256, 0, stream>>>(feat, weight + 13 * CIN * COUT, out, N);
    offset_k<<<dim3(96, 26), 256, 0, stream>>>(feat, weight, pairs, cnt, out);
    stats_k<<<256, 256, 0, stream>>>(out, stats, N);
    int nb4 = (N * (COUT / 4) + 255) / 256;
    norm_k<<<nb4, 256, 0, stream>>>(out, stats, gamma, beta, N);
}

// Round 8
// 264.264 us; speedup vs baseline: 1.1123x; 1.1123x over previous
//
#include <hip/hip_runtime.h>

// Sparse submanifold 3x3x3 conv (64->64) + BatchNorm(batch stats) + LeakyReLU(0.01)
// Rulebook strategy, occupancy bitmask, contention-free counters.
//   K1 memset cnt/stats (20KB) + occ bitmask (1.2MB)
//   K2 scatter: grid[lin]=i, atomicOr occ bit
//   K3 rulebook (block-aggregated LDS staging, padded global reservation)
//   K4 center GEMM: feat tile staged in LDS (coalesced, stride-68 pad), thread =
//      4 rows x 8 ch register block; W reads amortized 4x; conflict-free banks
//   K5 per-offset gather-GEMM: wave-per-2-pairs, lane=channel, coalesced atomics
//   K6 channel sum/sumsq reduction (padded atomics)
//   K7 normalize + leaky relu (in place on out)

#define DD 96
#define HH 320
#define WW 320
#define GRID_ELEMS (DD * HH * WW)
#define OCC_WORDS (GRID_ELEMS / 32)   // 1.2 MB; WW%32==0 => rows word-aligned
#define CIN 64
#define COUT 64
#define PAIR_CAP 16384
#define STAGE_CAP 40    // per-(block,k) staging; mean 3.9 hits, P(>40) ~ 0
#define TILE_R 128      // center_k rows per block
#define FSTRIDE 68      // LDS feat row stride (dwords): bank = 4g mod 32 -> conflict-free
#define EPSV 1e-5f
#define SLOPE 0.01f

__global__ void scatter_k(const int* __restrict__ coords, int* __restrict__ grid,
                          unsigned* __restrict__ occ, int N) {
    int i = blockIdx.x * 256 + threadIdx.x;
    if (i >= N) return;
    int z = coords[3 * i], y = coords[3 * i + 1], x = coords[3 * i + 2];
    int l = (z * HH + y) * WW + x;
    grid[l] = i;
    atomicOr(&occ[l >> 5], 1u << (l & 31));
}

// Per-voxel probe of L2-resident bitmask; hits staged in LDS; one padded global
// atomic per (block,k) reserves the compact range; bulk copy-out.
__global__ void rulebook_k(const int* __restrict__ coords, const int* __restrict__ grid,
                           const unsigned* __restrict__ occ,
                           int* __restrict__ cnt, int2* __restrict__ pairs, int N) {
    __shared__ int scnt[27];
    __shared__ int sbase[27];
    __shared__ int2 stage[27][STAGE_CAP];
    int tid = threadIdx.x;
    if (tid < 27) scnt[tid] = 0;
    __syncthreads();

    int i = blockIdx.x * 256 + tid;
    if (i < N) {
        int z = coords[3 * i], y = coords[3 * i + 1], x = coords[3 * i + 2];
        int lo = x > 0 ? x - 1 : 0;
        int hi = x < WW - 1 ? x + 1 : WW - 1;
        int wlo = lo >> 5, whi = hi >> 5;

        unsigned wa[9], wb9[9];
        int rwb[9];
#pragma unroll
        for (int r = 0; r < 9; ++r) {
            int zz = z + r / 3 - 1;
            int yy = y + r % 3 - 1;
            bool ok = ((unsigned)zz < DD) && ((unsigned)yy < HH);
            int base = (zz * HH + yy) * WW;      // word-aligned (WW % 32 == 0)
            rwb[r] = base;
            int wbase = base >> 5;
            wa[r]  = ok ? occ[wbase + wlo] : 0u;
            wb9[r] = ok ? occ[wbase + whi] : 0u;
        }
#pragma unroll
        for (int r = 0; r < 9; ++r) {
            for (int xx = lo; xx <= hi; ++xx) {
                if (r == 4 && xx == x) continue;          // center handled by center_k
                unsigned w = ((xx >> 5) == wlo) ? wa[r] : wb9[r];
                if ((w >> (xx & 31)) & 1u) {
                    int j = grid[rwb[r] + xx];
                    int k = r * 3 + (xx - x + 1);         // 0..26, never 13
                    int pos = atomicAdd(&scnt[k], 1);     // LDS atomic: cheap
                    if (pos < STAGE_CAP) stage[k][pos] = make_int2(i, j);
                }
            }
        }
    }
    __syncthreads();
    if (tid < 27) {
        int c = scnt[tid];
        if (c > STAGE_CAP) c = STAGE_CAP;
        scnt[tid] = c;
        if (c > 0) sbase[tid] = atomicAdd(&cnt[tid * 32], c);  // 128B-padded counters
    }
    __syncthreads();
    for (int s = tid; s < 27 * STAGE_CAP; s += 256) {
        int k = s / STAGE_CAP, p = s % STAGE_CAP;
        if (p < scnt[k]) {
            int pos = sbase[k] + p;
            if (pos < PAIR_CAP) pairs[k * PAIR_CAP + pos] = stage[k][p];
        }
    }
}

// Dense GEMM, 128-row tile in LDS. Thread = 4 rows (strided by 32) x 8 channels.
// Global reads/writes fully coalesced; LDS reads conflict-free (stride 68);
// W-fragment reads amortized over 4 rows in registers.
__global__ void center_k(const float* __restrict__ feat, const float* __restrict__ w13,
                         float* __restrict__ out, int N) {
    __shared__ float wl[CIN * COUT];          // 16 KB
    __shared__ float fl[TILE_R * FSTRIDE];    // 34.8 KB
    {
        const float4* ws4 = (const float4*)w13;
        float4* wl4 = (float4*)wl;
        for (int t = threadIdx.x; t < CIN * COUT / 4; t += 256) wl4[t] = ws4[t];
    }
    int base_row = blockIdx.x * TILE_R;
    for (int t = threadIdx.x; t < TILE_R * 16; t += 256) {
        int r = t >> 4, c4 = t & 15;
        int gr = base_row + r;
        float4 v = (gr < N) ? ((const float4*)feat)[(size_t)gr * 16 + c4]
                            : make_float4(0.f, 0.f, 0.f, 0.f);
        *(float4*)&fl[r * FSTRIDE + c4 * 4] = v;
    }
    __syncthreads();

    int g = threadIdx.x >> 3;            // 0..31: row within 32-row stripe
    int c0 = (threadIdx.x & 7) * 8;      // 8-channel group
    float4 acc[4][2];
#pragma unroll
    for (int r = 0; r < 4; ++r) {
        acc[r][0] = make_float4(0.f, 0.f, 0.f, 0.f);
        acc[r][1] = make_float4(0.f, 0.f, 0.f, 0.f);
    }
#pragma unroll 4
    for (int ci4 = 0; ci4 < 16; ++ci4) {
        float4 f[4];
#pragma unroll
        for (int r = 0; r < 4; ++r)
            f[r] = *(const float4*)&fl[(g + 32 * r) * FSTRIDE + ci4 * 4];
#pragma unroll
        for (int u = 0; u < 4; ++u) {
            float4 wa = *(const float4*)&wl[(ci4 * 4 + u) * COUT + c0];
            float4 wb = *(const float4*)&wl[(ci4 * 4 + u) * COUT + c0 + 4];
#pragma unroll
            for (int r = 0; r < 4; ++r) {
                float fv = (&f[r].x)[u];
                acc[r][0].x += fv * wa.x;
                acc[r][0].y += fv * wa.y;
                acc[r][0].z += fv * wa.z;
                acc[r][0].w += fv * wa.w;
                acc[r][1].x += fv * wb.x;
                acc[r][1].y += fv * wb.y;
                acc[r][1].z += fv * wb.z;
                acc[r][1].w += fv * wb.w;
            }
        }
    }
    float4* o4 = (float4*)out;
#pragma unroll
    for (int r = 0; r < 4; ++r) {
        int row = base_row + g + 32 * r;
        if (row < N) {
            size_t base = (size_t)row * 16 + (c0 >> 2);
            o4[base] = acc[r][0];
            o4[base + 1] = acc[r][1];
        }
    }
}

// Wave-per-2-pairs: lane = output channel; each wl read feeds both accumulators.
// f[j] float4 reads are wave-uniform (broadcast); atomicAdd per pair is ONE
// contiguous 256B region (4 lines).
__global__ void offset_k(const float* __restrict__ feat, const float* __restrict__ weight,
                         const int2* __restrict__ pairs, const int* __restrict__ cnt,
                         float* __restrict__ out) {
    int k = blockIdx.y;
    if (k >= 13) ++k;  // skip center
    int ck = cnt[k * 32];
    if (ck > PAIR_CAP) ck = PAIR_CAP;
    __shared__ float wl[CIN * COUT];
    {
        const float4* ws4 = (const float4*)(weight + (size_t)k * CIN * COUT);
        float4* wl4 = (float4*)wl;
        for (int t = threadIdx.x; t < CIN * COUT / 4; t += 256) wl4[t] = ws4[t];
    }
    __syncthreads();
    int wave = threadIdx.x >> 6;   // 0..3
    int lane = threadIdx.x & 63;   // output channel
    for (int p = (int)blockIdx.x * 8 + wave * 2; p < ck; p += (int)gridDim.x * 8) {
        int2 prA = pairs[k * PAIR_CAP + p];
        bool hasB = (p + 1) < ck;
        int2 prB = hasB ? pairs[k * PAIR_CAP + p + 1] : prA;
        const float4* frA = (const float4*)(feat + (size_t)prA.y * CIN);
        const float4* frB = (const float4*)(feat + (size_t)prB.y * CIN);
        float accA = 0.f, accB = 0.f;
#pragma unroll
        for (int ci4 = 0; ci4 < CIN / 4; ++ci4) {
            float4 fa = frA[ci4];                       // wave-uniform -> broadcast
            float4 fb = frB[ci4];
#pragma unroll
            for (int u = 0; u < 4; ++u) {
                float w = wl[(ci4 * 4 + u) * COUT + lane];
                accA += (&fa.x)[u] * w;
                accB += (&fb.x)[u] * w;
            }
        }
        atomicAdd(&out[(size_t)prA.x * COUT + lane], accA);  // coalesced 256B region
        if (hasB) atomicAdd(&out[(size_t)prB.x * COUT + lane], accB);
    }
}

// Padded stats: stats[c*32] = sum_c, stats[(64+c)*32] = sumsq_c (128B per counter)
__global__ void stats_k(const float* __restrict__ out, float* __restrict__ stats, int N) {
    __shared__ float ssum[4][64];
    __shared__ float ssq[4][64];
    int c = threadIdx.x & 63, g = threadIdx.x >> 6;
    float s = 0.f, q = 0.f;
    for (int r = blockIdx.x * 4 + g; r < N; r += gridDim.x * 4) {
        float v = out[(size_t)r * 64 + c];
        s += v;
        q += v * v;
    }
    ssum[g][c] = s;
    ssq[g][c] = q;
    __syncthreads();
    if (threadIdx.x < 64) {
        float ts = ssum[0][c] + ssum[1][c] + ssum[2][c] + ssum[3][c];
        float tq = ssq[0][c] + ssq[1][c] + ssq[2][c] + ssq[3][c];
        atomicAdd(&stats[c * 32], ts);
        atomicAdd(&stats[(64 + c) * 32], tq);
    }
}

__global__ void norm_k(float* __restrict__ out, const float* __restrict__ stats,
                       const float* __restrict__ gamma, const float* __restrict__ beta, int N) {
    int idx = (int)blockIdx.x * 256 + threadIdx.x;
    int total = N * (COUT / 4);
    if (idx >= total) return;
    int c0 = (idx & 15) * 4;
    float inv = 1.0f / (float)N;
    float4 v = ((const float4*)out)[idx];
    float4 r;
#pragma unroll
    for (int u = 0; u < 4; ++u) {
        int c = c0 + u;
        float mean = stats[c * 32] * inv;
        float var = stats[(64 + c) * 32] * inv - mean * mean;
        if (var < 0.f) var = 0.f;
        float sc = gamma[c] * rsqrtf(var + EPSV);
        float sh = beta[c] - mean * sc;
        float y = (&v.x)[u] * sc + sh;
        (&r.x)[u] = (y >= 0.f) ? y : SLOPE * y;
    }
    ((float4*)out)[idx] = r;
}

extern "C" void kernel_launch(void* const* d_in, const int* in_sizes, int n_in,
                              void* d_out, int out_size, void* d_ws, size_t ws_size,
                              hipStream_t stream) {
    const float* feat   = (const float*)d_in[0];
    const int*   coords = (const int*)d_in[1];
    const float* weight = (const float*)d_in[2];
    const float* gamma  = (const float*)d_in[3];
    const float* beta   = (const float*)d_in[4];
    float* out = (float*)d_out;
    int N = in_sizes[0] / CIN;

    // workspace layout (~44.1 MB)
    char* ws = (char*)d_ws;
    int* grid = (int*)ws;                                   // 39.32 MB (gated by occ, no memset)
    size_t off = (size_t)GRID_ELEMS * 4;
    int* cnt = (int*)(ws + off);                            // 27*32 ints padded -> 4KB slot
    float* stats = (float*)(ws + off + 4096);               // 128*32 floats padded = 16KB
    int2* pairs = (int2*)(ws + off + 4096 + 16384);         // 27*PAIR_CAP*8 = 3.54 MB
    size_t occ_off = off + 4096 + 16384 + (size_t)27 * PAIR_CAP * 8;
    unsigned* occ = (unsigned*)(ws + occ_off);              // 1.2 MB bitmask

    hipMemsetAsync(ws + off, 0, 4096 + 16384, stream);      // counters + stats
    hipMemsetAsync(occ, 0, (size_t)OCC_WORDS * 4, stream);  // bitmask = 0

    int nb = (N + 255) / 256;
    scatter_k<<<nb, 256, 0, stream>>>(coords, grid, occ, N);
    rulebook_k<<<nb, 256, 0, stream>>>(coords, grid, occ, cnt, pairs, N);
    int nbc = (N + TILE_R - 1) / TILE_R;
    center_k<<<nbc, 256, 0, stream>>>(feat, weight + 13 * CIN * COUT, out, N);
    offset_k<<<dim3(96, 26), 256, 0, stream>>>(feat, weight, pairs, cnt, out);
    stats_k<<<256, 256, 0, stream>>>(out, stats, N);
    int nb4 = (N * (COUT / 4) + 255) / 256;
    norm_k<<<nb4, 256, 0, stream>>>(out, stats, gamma, beta, N);
}